// Round 3
// baseline (272.186 us; speedup 1.0000x reference)
//
#include <hip/hip_runtime.h>
#include <hip/hip_bf16.h>

// VolatilityModulatedAttention: B=2, S=4096, H=512, NH=8, HD=64
// Round 2: S^T MFMA orientation (b64 packed P writes), V-frag reuse across
// q-subtiles, no-max exp2 softmax with prescaled Q, v_perm packed bf16.

#define S_LEN 4096
#define NHEAD 8
#define HD 64
#define HTOT 512

typedef __attribute__((ext_vector_type(8))) short short8;
typedef __attribute__((ext_vector_type(4))) float floatx4;

#if __has_builtin(__builtin_amdgcn_exp2f)
#define EXP2F(x) __builtin_amdgcn_exp2f(x)
#else
#define EXP2F(x) exp2f(x)
#endif

// pack two fp32 -> two bf16 in one dword (round-half-up, 1 ulp-class error)
__device__ __forceinline__ unsigned pack_bf16(float a, float b) {
    unsigned ua = __builtin_bit_cast(unsigned, a) + 0x8000u;
    unsigned ub = __builtin_bit_cast(unsigned, b) + 0x8000u;
    return __builtin_amdgcn_perm(ub, ua, 0x07060302u);  // lo=bf(a), hi=bf(b)
}

__device__ __forceinline__ unsigned short f2bf(float x) {
    unsigned u = __builtin_bit_cast(unsigned, x) + 0x8000u;
    return (unsigned short)(u >> 16);
}

// ---------------------------------------------------------------------------
// Fused prepass. Blocks [0,2048): K fp32 -> bf16 (same layout).
// Blocks [2048,3072): V fp32 [B,S,512] -> bf16 per-head transpose
// Vt[B*8][64][4096].
// ---------------------------------------------------------------------------
__global__ __launch_bounds__(256) void prep_kernel(
    const float* __restrict__ K, unsigned short* __restrict__ K16,
    const float* __restrict__ V, unsigned short* __restrict__ Vt)
{
    const int tid = threadIdx.x;
    if (blockIdx.x < 2048) {
        size_t i = ((size_t)blockIdx.x * 256 + tid) * 8;
        float4 a = *(const float4*)(K + i);
        float4 b = *(const float4*)(K + i + 4);
        unsigned o[4] = {pack_bf16(a.x, a.y), pack_bf16(a.z, a.w),
                         pack_bf16(b.x, b.y), pack_bf16(b.z, b.w)};
        *(short8*)(K16 + i) = *(short8*)o;
    } else {
        __shared__ unsigned short T[64 * 66];   // [d][s]
        const int blk = blockIdx.x - 2048;
        const int st = blk & 63;
        const int bh = blk >> 6;
        const int b = bh >> 3, h = bh & 7;
        const float* src = V + ((size_t)b * S_LEN + st * 64) * HTOT + h * HD;
        for (int i = 0; i < 4; i++) {
            int idx = tid + i * 256;            // 64 s-rows x 16 float4 chunks
            int s = idx >> 4, c4 = idx & 15;
            float4 v = *(const float4*)(src + (size_t)s * HTOT + c4 * 4);
            T[(c4 * 4 + 0) * 66 + s] = f2bf(v.x);
            T[(c4 * 4 + 1) * 66 + s] = f2bf(v.y);
            T[(c4 * 4 + 2) * 66 + s] = f2bf(v.z);
            T[(c4 * 4 + 3) * 66 + s] = f2bf(v.w);
        }
        __syncthreads();
        unsigned short* dst = Vt + ((size_t)bh * 64) * S_LEN + st * 64;
        for (int i = 0; i < 2; i++) {
            int idx = tid + i * 256;            // 64 d-rows x 8 short8 chunks
            int d = idx >> 3, c8 = idx & 7;
            // rowlen 66 is not 16B-aligned per row; use two b64 reads
            uint2 lo = *(const uint2*)&T[d * 66 + c8 * 8];
            uint2 hi = *(const uint2*)&T[d * 66 + c8 * 8 + 4];
            unsigned o[4] = {lo.x, lo.y, hi.x, hi.y};
            *(short8*)(dst + (size_t)d * S_LEN + c8 * 8) = *(short8*)o;
        }
    }
}

// ---------------------------------------------------------------------------
// Flash attention. Grid: 512 = B(2)*NH(8)*(S/128=32 q-tiles). Block: 4 waves;
// each wave owns 32 q rows (2 subtiles of 16). QK^T computed transposed
// (S^T = K*Q^T) so P-writes are packed b64 into row-major P[q][key].
// Softmax: p = exp2(S~ + nc2*d^2), no running max (shift-invariant, bounded).
// ---------------------------------------------------------------------------
__global__ __launch_bounds__(256) void attn_kernel(
    const float* __restrict__ Q, const unsigned short* __restrict__ K16,
    const unsigned short* __restrict__ Vt,
    const float* __restrict__ risk_sigma, const float* __restrict__ risk_lambda,
    unsigned short* __restrict__ ctx_bf16)
{
    __shared__ unsigned short QPsh[128 * 72];   // Q tile, then per-wave P
    __shared__ unsigned short Ksh[64 * 72];     // [key][d]
    __shared__ unsigned short Vsh[64 * 72];     // [d][key]

    const int tid  = threadIdx.x;
    const int wave = tid >> 6;
    const int lane = tid & 63;
    const int quad = lane >> 4;
    const int ln   = lane & 15;

    const int bid = blockIdx.x;
    const int qt  = bid & 31;
    const int h   = (bid >> 5) & 7;
    const int b   = bid >> 8;
    const int qbase = qt * 128;

    float sig = risk_sigma[b];
    sig = fminf(fmaxf(sig, 0.001f), 0.2f);
    const float sn   = (sig - 0.001f) * (1.0f / 0.199f);
    const float coef = risk_lambda[0] * 0.1f * sn;
    // exp2-domain quadratic coefficient: nc2 = -coef/S^2/ln2
    const float nc2 = -coef * (1.0f / 4096.0f) * (1.0f / 4096.0f) * 1.4426950408889634f;
    const float qscale = 0.125f * 1.4426950408889634f;  // 1/8 / ln2

    const float* Qb = Q + (size_t)b * S_LEN * HTOT + (size_t)h * HD;
    const unsigned short* Kb = K16 + (size_t)b * S_LEN * HTOT + (size_t)h * HD;
    const unsigned short* Vb = Vt + ((size_t)(b * 8 + h) * 64) * S_LEN;

    // ---- stage Q tile (128 x 64), prescaled fp32 -> bf16 ----
    for (int i = 0; i < 8; i++) {
        int idx = tid + i * 256;            // 128 rows x 16 float4 chunks
        int r = idx >> 4, c4 = idx & 15;
        float4 v = *(const float4*)(Qb + (size_t)(qbase + r) * HTOT + c4 * 4);
        uint2 o;
        o.x = pack_bf16(v.x * qscale, v.y * qscale);
        o.y = pack_bf16(v.z * qscale, v.w * qscale);
        *(uint2*)&QPsh[r * 72 + c4 * 4] = o;
    }
    __syncthreads();

    // Q A-frags (as B-operand = Q^T): subtile nt covers q = qa + nt*16 + ln
    short8 qf[2][2];
    for (int nt = 0; nt < 2; nt++) {
        qf[nt][0] = *(const short8*)&QPsh[(wave * 32 + nt * 16 + ln) * 72 + quad * 8];
        qf[nt][1] = *(const short8*)&QPsh[(wave * 32 + nt * 16 + ln) * 72 + 32 + quad * 8];
    }
    unsigned short* Pw = &QPsh[wave * 32 * 72];   // wave-private P [32 q][72]

    floatx4 Oacc[2][4];
    for (int nt = 0; nt < 2; nt++)
        for (int dt = 0; dt < 4; dt++) Oacc[nt][dt] = (floatx4){0.f, 0.f, 0.f, 0.f};
    float lp[2] = {0.f, 0.f};   // per-lane partial sum for q = qa + nt*16 + ln

    const int qa = qbase + wave * 32;

    for (int kt = 0; kt < S_LEN / 64; ++kt) {
        const int kbase = kt * 64;
        __syncthreads();
        for (int i = 0; i < 2; i++) {
            int idx = tid + i * 256;        // 64 rows x 8 short8 chunks
            int r = idx >> 3, c8 = idx & 7;
            short8 kv = *(const short8*)(Kb + (size_t)(kbase + r) * HTOT + c8 * 8);
            *(short8*)&Ksh[r * 72 + c8 * 8] = kv;
            short8 vv = *(const short8*)(Vb + (size_t)r * S_LEN + kbase + c8 * 8);
            *(short8*)&Vsh[r * 72 + c8 * 8] = vv;
        }
        __syncthreads();

        // ---- S^T = K * Q^T, then softmax + packed P write ----
        const float dq = (float)(qa + ln - kbase);
        for (int jt = 0; jt < 4; jt++) {
            short8 ak0 = *(const short8*)&Ksh[(jt * 16 + ln) * 72 + quad * 8];
            short8 ak1 = *(const short8*)&Ksh[(jt * 16 + ln) * 72 + 32 + quad * 8];
            #pragma unroll
            for (int nt = 0; nt < 2; nt++) {
                floatx4 s = (floatx4){0.f, 0.f, 0.f, 0.f};
                s = __builtin_amdgcn_mfma_f32_16x16x32_bf16(ak0, qf[nt][0], s, 0, 0, 0);
                s = __builtin_amdgcn_mfma_f32_16x16x32_bf16(ak1, qf[nt][1], s, 0, 0, 0);
                // lane holds keys kbase+jt*16+quad*4+r (r=0..3), q = qa+nt*16+ln
                float d = dq + (float)(nt * 16 - jt * 16 - quad * 4);
                float p[4];
                #pragma unroll
                for (int r = 0; r < 4; r++) {
                    float arg = __builtin_fmaf(nc2, d * d, s[r]);
                    p[r] = EXP2F(arg);
                    lp[nt] += p[r];
                    d -= 1.0f;
                }
                uint2 o;
                o.x = pack_bf16(p[0], p[1]);
                o.y = pack_bf16(p[2], p[3]);
                *(uint2*)&Pw[(nt * 16 + ln) * 72 + jt * 16 + quad * 4] = o;
            }
        }
        asm volatile("s_waitcnt lgkmcnt(0)" ::: "memory");
        __builtin_amdgcn_wave_barrier();

        // ---- PV: O[32 q x 64 d] += P * V (V-frags reused across subtiles) ----
        short8 pf[2][2];
        for (int nt = 0; nt < 2; nt++) {
            pf[nt][0] = *(const short8*)&Pw[(nt * 16 + ln) * 72 + quad * 8];
            pf[nt][1] = *(const short8*)&Pw[(nt * 16 + ln) * 72 + 32 + quad * 8];
        }
        for (int dt = 0; dt < 4; dt++) {
            short8 bv0 = *(const short8*)&Vsh[(dt * 16 + ln) * 72 + quad * 8];
            short8 bv1 = *(const short8*)&Vsh[(dt * 16 + ln) * 72 + 32 + quad * 8];
            #pragma unroll
            for (int nt = 0; nt < 2; nt++) {
                Oacc[nt][dt] = __builtin_amdgcn_mfma_f32_16x16x32_bf16(pf[nt][0], bv0, Oacc[nt][dt], 0, 0, 0);
                Oacc[nt][dt] = __builtin_amdgcn_mfma_f32_16x16x32_bf16(pf[nt][1], bv1, Oacc[nt][dt], 0, 0, 0);
            }
        }
    }

    // ---- epilogue: l reduce (2 shfl) + redistribute, ctx = O/l -> bf16 ----
    for (int nt = 0; nt < 2; nt++) {
        float l = lp[nt];
        l += __shfl_xor(l, 16, 64);
        l += __shfl_xor(l, 32, 64);
        float rl = 1.0f / l;                    // valid for q = qa+nt*16+ln
        float rlr[4];
        #pragma unroll
        for (int r = 0; r < 4; r++) rlr[r] = __shfl(rl, quad * 4 + r, 64);
        for (int dt = 0; dt < 4; dt++)
            for (int r = 0; r < 4; r++) {
                int q = qa + nt * 16 + quad * 4 + r;
                int d = dt * 16 + ln;
                ctx_bf16[((size_t)b * S_LEN + q) * HTOT + h * HD + d] =
                    f2bf(Oacc[nt][dt][r] * rlr[r]);
            }
    }
}

// ---------------------------------------------------------------------------
// Projection GEMM: out[m][n] = sum_k ctx[m][k] * W[n][k] + bias[n]
// ---------------------------------------------------------------------------
__global__ __launch_bounds__(256) void proj_kernel(
    const unsigned short* __restrict__ A,  // ctx bf16 [8192 x 512]
    const float* __restrict__ W,           // [512 x 512] fp32
    const float* __restrict__ bias,        // [512]
    float* __restrict__ out)               // [8192 x 512] fp32
{
    __shared__ unsigned short Ash[128 * 40];
    __shared__ unsigned short Bsh[128 * 40];
    const int tid = threadIdx.x;
    const int wave = tid >> 6, lane = tid & 63, quad = lane >> 4, ln = lane & 15;
    const int wr = wave >> 1, wc = wave & 1;
    const int mblock = blockIdx.y * 128;
    const int nblock = blockIdx.x * 128;

    floatx4 acc[4][4];
    for (int i = 0; i < 4; i++)
        for (int j = 0; j < 4; j++) acc[i][j] = (floatx4){0.f, 0.f, 0.f, 0.f};

    for (int kt = 0; kt < 512 / 32; ++kt) {
        const int k0 = kt * 32;
        __syncthreads();
        for (int i = 0; i < 2; i++) {
            int idx = tid + i * 256;
            int r = idx >> 2, c8 = idx & 3;
            short8 v = *(const short8*)&A[(size_t)(mblock + r) * 512 + k0 + c8 * 8];
            *(short8*)&Ash[r * 40 + c8 * 8] = v;
        }
        for (int i = 0; i < 4; i++) {
            int idx = tid + i * 256;
            int r = idx >> 3, c4 = idx & 7;
            float4 v = *(const float4*)&W[(size_t)(nblock + r) * 512 + k0 + c4 * 4];
            uint2 o;
            o.x = pack_bf16(v.x, v.y);
            o.y = pack_bf16(v.z, v.w);
            *(uint2*)&Bsh[r * 40 + c4 * 4] = o;
        }
        __syncthreads();
        short8 af[4], bf[4];
        for (int i = 0; i < 4; i++)
            af[i] = *(const short8*)&Ash[(wr * 64 + i * 16 + ln) * 40 + quad * 8];
        for (int j = 0; j < 4; j++)
            bf[j] = *(const short8*)&Bsh[(wc * 64 + j * 16 + ln) * 40 + quad * 8];
        for (int i = 0; i < 4; i++)
            for (int j = 0; j < 4; j++)
                acc[i][j] = __builtin_amdgcn_mfma_f32_16x16x32_bf16(af[i], bf[j], acc[i][j], 0, 0, 0);
    }

    for (int i = 0; i < 4; i++) {
        int row = mblock + wr * 64 + i * 16 + quad * 4;
        for (int j = 0; j < 4; j++) {
            int col = nblock + wc * 64 + j * 16 + ln;
            float bv = bias[col];
            for (int r = 0; r < 4; r++)
                out[(size_t)(row + r) * 512 + col] = acc[i][j][r] + bv;
        }
    }
}

extern "C" void kernel_launch(void* const* d_in, const int* in_sizes, int n_in,
                              void* d_out, int out_size, void* d_ws, size_t ws_size,
                              hipStream_t stream) {
    const float* Q    = (const float*)d_in[0];
    const float* K    = (const float*)d_in[1];
    const float* V    = (const float*)d_in[2];
    const float* sig  = (const float*)d_in[3];
    const float* lam  = (const float*)d_in[4];
    const float* W    = (const float*)d_in[5];
    const float* bias = (const float*)d_in[6];

    unsigned short* ctx = (unsigned short*)d_ws;                        // 8 MB
    unsigned short* K16 = (unsigned short*)((char*)d_ws + (8u << 20));  // 8 MB
    unsigned short* Vt  = (unsigned short*)((char*)d_ws + (16u << 20)); // 8 MB
    float* out = (float*)d_out;

    prep_kernel<<<dim3(3072), dim3(256), 0, stream>>>(K, K16, V, Vt);
    attn_kernel<<<dim3(512), dim3(256), 0, stream>>>(Q, K16, Vt, sig, lam, ctx);
    proj_kernel<<<dim3(4, 64), dim3(256), 0, stream>>>(ctx, W, bias, out);
}

// Round 4
// 247.542 us; speedup vs baseline: 1.0996x; 1.0996x over previous
//
#include <hip/hip_runtime.h>
#include <hip/hip_bf16.h>

// VolatilityModulatedAttention: B=2, S=4096, H=512, NH=8, HD=64
// Round 3: K-split x2 (grid 512->1024, 2->4 blocks/CU — R2 showed 47% idle
// at 2 waves/SIMD). Per-half-normalized fp16 partial ctx stored in d_out
// (16 MB exactly), l-sums in ws; combine kernel produces bf16 ctx.

#define S_LEN 4096
#define NHEAD 8
#define HD 64
#define HTOT 512

typedef __attribute__((ext_vector_type(8))) short short8;
typedef __attribute__((ext_vector_type(4))) float floatx4;
typedef __attribute__((ext_vector_type(2))) _Float16 half2v;

#if __has_builtin(__builtin_amdgcn_exp2f)
#define EXP2F(x) __builtin_amdgcn_exp2f(x)
#else
#define EXP2F(x) exp2f(x)
#endif

// pack two fp32 -> two bf16 in one dword (round-half-up, 1 ulp-class error)
__device__ __forceinline__ unsigned pack_bf16(float a, float b) {
    unsigned ua = __builtin_bit_cast(unsigned, a) + 0x8000u;
    unsigned ub = __builtin_bit_cast(unsigned, b) + 0x8000u;
    return __builtin_amdgcn_perm(ub, ua, 0x07060302u);  // lo=bf(a), hi=bf(b)
}

__device__ __forceinline__ unsigned short f2bf(float x) {
    unsigned u = __builtin_bit_cast(unsigned, x) + 0x8000u;
    return (unsigned short)(u >> 16);
}

// ---------------------------------------------------------------------------
// Fused prepass. Blocks [0,2048): K fp32 -> bf16 (same layout).
// Blocks [2048,3072): V fp32 [B,S,512] -> bf16 per-head transpose
// Vt[B*8][64][4096].
// ---------------------------------------------------------------------------
__global__ __launch_bounds__(256) void prep_kernel(
    const float* __restrict__ K, unsigned short* __restrict__ K16,
    const float* __restrict__ V, unsigned short* __restrict__ Vt)
{
    const int tid = threadIdx.x;
    if (blockIdx.x < 2048) {
        size_t i = ((size_t)blockIdx.x * 256 + tid) * 8;
        float4 a = *(const float4*)(K + i);
        float4 b = *(const float4*)(K + i + 4);
        unsigned o[4] = {pack_bf16(a.x, a.y), pack_bf16(a.z, a.w),
                         pack_bf16(b.x, b.y), pack_bf16(b.z, b.w)};
        *(short8*)(K16 + i) = *(short8*)o;
    } else {
        __shared__ unsigned short T[64 * 66];   // [d][s]
        const int blk = blockIdx.x - 2048;
        const int st = blk & 63;
        const int bh = blk >> 6;
        const int b = bh >> 3, h = bh & 7;
        const float* src = V + ((size_t)b * S_LEN + st * 64) * HTOT + h * HD;
        for (int i = 0; i < 4; i++) {
            int idx = tid + i * 256;            // 64 s-rows x 16 float4 chunks
            int s = idx >> 4, c4 = idx & 15;
            float4 v = *(const float4*)(src + (size_t)s * HTOT + c4 * 4);
            T[(c4 * 4 + 0) * 66 + s] = f2bf(v.x);
            T[(c4 * 4 + 1) * 66 + s] = f2bf(v.y);
            T[(c4 * 4 + 2) * 66 + s] = f2bf(v.z);
            T[(c4 * 4 + 3) * 66 + s] = f2bf(v.w);
        }
        __syncthreads();
        unsigned short* dst = Vt + ((size_t)bh * 64) * S_LEN + st * 64;
        for (int i = 0; i < 2; i++) {
            int idx = tid + i * 256;            // 64 d-rows x 8 short8 chunks
            int d = idx >> 3, c8 = idx & 7;
            uint2 lo = *(const uint2*)&T[d * 66 + c8 * 8];
            uint2 hi = *(const uint2*)&T[d * 66 + c8 * 8 + 4];
            unsigned o[4] = {lo.x, lo.y, hi.x, hi.y};
            *(short8*)(dst + (size_t)d * S_LEN + c8 * 8) = *(short8*)o;
        }
    }
}

// ---------------------------------------------------------------------------
// Flash attention, K-split x2. Grid: 1024 = B(2)*NH(8)*qt(32)*ks(2).
// Block: 4 waves x 32 q rows; each block does keys [ks*2048, ks*2048+2048).
// Emits per-half-normalized ctx partial (fp16) + l partial.
// ---------------------------------------------------------------------------
__global__ __launch_bounds__(256) void attn_kernel(
    const float* __restrict__ Q, const unsigned short* __restrict__ K16,
    const unsigned short* __restrict__ Vt,
    const float* __restrict__ risk_sigma, const float* __restrict__ risk_lambda,
    _Float16* __restrict__ Cpart, float* __restrict__ Lpart)
{
    __shared__ unsigned short QPsh[128 * 72];   // Q tile, then per-wave P
    __shared__ unsigned short Ksh[64 * 72];     // [key][d]
    __shared__ unsigned short Vsh[64 * 72];     // [d][key]

    const int tid  = threadIdx.x;
    const int wave = tid >> 6;
    const int lane = tid & 63;
    const int quad = lane >> 4;
    const int ln   = lane & 15;

    const int bid = blockIdx.x;                 // = ((b*8+h)*32+qt)*2+ks
    const int ks  = bid & 1;
    const int qt  = (bid >> 1) & 31;
    const int h   = (bid >> 6) & 7;
    const int b   = bid >> 9;
    const int qbase = qt * 128;

    float sig = risk_sigma[b];
    sig = fminf(fmaxf(sig, 0.001f), 0.2f);
    const float sn   = (sig - 0.001f) * (1.0f / 0.199f);
    const float coef = risk_lambda[0] * 0.1f * sn;
    const float nc2 = -coef * (1.0f / 4096.0f) * (1.0f / 4096.0f) * 1.4426950408889634f;
    const float qscale = 0.125f * 1.4426950408889634f;  // 1/8 / ln2

    const float* Qb = Q + (size_t)b * S_LEN * HTOT + (size_t)h * HD;
    const unsigned short* Kb = K16 + (size_t)b * S_LEN * HTOT + (size_t)h * HD;
    const unsigned short* Vb = Vt + ((size_t)(b * 8 + h) * 64) * S_LEN;

    // ---- stage Q tile (128 x 64), prescaled fp32 -> bf16 ----
    for (int i = 0; i < 8; i++) {
        int idx = tid + i * 256;            // 128 rows x 16 float4 chunks
        int r = idx >> 4, c4 = idx & 15;
        float4 v = *(const float4*)(Qb + (size_t)(qbase + r) * HTOT + c4 * 4);
        uint2 o;
        o.x = pack_bf16(v.x * qscale, v.y * qscale);
        o.y = pack_bf16(v.z * qscale, v.w * qscale);
        *(uint2*)&QPsh[r * 72 + c4 * 4] = o;
    }
    __syncthreads();

    short8 qf[2][2];
    for (int nt = 0; nt < 2; nt++) {
        qf[nt][0] = *(const short8*)&QPsh[(wave * 32 + nt * 16 + ln) * 72 + quad * 8];
        qf[nt][1] = *(const short8*)&QPsh[(wave * 32 + nt * 16 + ln) * 72 + 32 + quad * 8];
    }
    unsigned short* Pw = &QPsh[wave * 32 * 72];   // wave-private P [32 q][72]

    floatx4 Oacc[2][4];
    for (int nt = 0; nt < 2; nt++)
        for (int dt = 0; dt < 4; dt++) Oacc[nt][dt] = (floatx4){0.f, 0.f, 0.f, 0.f};
    float lp[2] = {0.f, 0.f};

    const int qa = qbase + wave * 32;

    for (int kt = ks * 32; kt < ks * 32 + 32; ++kt) {
        const int kbase = kt * 64;
        __syncthreads();
        for (int i = 0; i < 2; i++) {
            int idx = tid + i * 256;        // 64 rows x 8 short8 chunks
            int r = idx >> 3, c8 = idx & 7;
            short8 kv = *(const short8*)(Kb + (size_t)(kbase + r) * HTOT + c8 * 8);
            *(short8*)&Ksh[r * 72 + c8 * 8] = kv;
            short8 vv = *(const short8*)(Vb + (size_t)r * S_LEN + kbase + c8 * 8);
            *(short8*)&Vsh[r * 72 + c8 * 8] = vv;
        }
        __syncthreads();

        // ---- S^T = K * Q^T, softmax, packed b64 P write ----
        const float dq = (float)(qa + ln - kbase);
        for (int jt = 0; jt < 4; jt++) {
            short8 ak0 = *(const short8*)&Ksh[(jt * 16 + ln) * 72 + quad * 8];
            short8 ak1 = *(const short8*)&Ksh[(jt * 16 + ln) * 72 + 32 + quad * 8];
            #pragma unroll
            for (int nt = 0; nt < 2; nt++) {
                floatx4 s = (floatx4){0.f, 0.f, 0.f, 0.f};
                s = __builtin_amdgcn_mfma_f32_16x16x32_bf16(ak0, qf[nt][0], s, 0, 0, 0);
                s = __builtin_amdgcn_mfma_f32_16x16x32_bf16(ak1, qf[nt][1], s, 0, 0, 0);
                float d = dq + (float)(nt * 16 - jt * 16 - quad * 4);
                float p[4];
                #pragma unroll
                for (int r = 0; r < 4; r++) {
                    float arg = __builtin_fmaf(nc2, d * d, s[r]);
                    p[r] = EXP2F(arg);
                    lp[nt] += p[r];
                    d -= 1.0f;
                }
                uint2 o;
                o.x = pack_bf16(p[0], p[1]);
                o.y = pack_bf16(p[2], p[3]);
                *(uint2*)&Pw[(nt * 16 + ln) * 72 + jt * 16 + quad * 4] = o;
            }
        }
        asm volatile("s_waitcnt lgkmcnt(0)" ::: "memory");
        __builtin_amdgcn_wave_barrier();

        // ---- PV (V-frags reused across subtiles) ----
        short8 pf[2][2];
        for (int nt = 0; nt < 2; nt++) {
            pf[nt][0] = *(const short8*)&Pw[(nt * 16 + ln) * 72 + quad * 8];
            pf[nt][1] = *(const short8*)&Pw[(nt * 16 + ln) * 72 + 32 + quad * 8];
        }
        for (int dt = 0; dt < 4; dt++) {
            short8 bv0 = *(const short8*)&Vsh[(dt * 16 + ln) * 72 + quad * 8];
            short8 bv1 = *(const short8*)&Vsh[(dt * 16 + ln) * 72 + 32 + quad * 8];
            #pragma unroll
            for (int nt = 0; nt < 2; nt++) {
                Oacc[nt][dt] = __builtin_amdgcn_mfma_f32_16x16x32_bf16(pf[nt][0], bv0, Oacc[nt][dt], 0, 0, 0);
                Oacc[nt][dt] = __builtin_amdgcn_mfma_f32_16x16x32_bf16(pf[nt][1], bv1, Oacc[nt][dt], 0, 0, 0);
            }
        }
    }

    // ---- epilogue: per-half l, normalized fp16 partial ctx ----
    _Float16* Cw = Cpart + (size_t)bid * (128 * 64);
    for (int nt = 0; nt < 2; nt++) {
        float l = lp[nt];
        l += __shfl_xor(l, 16, 64);
        l += __shfl_xor(l, 32, 64);
        if (quad == 0)
            Lpart[bid * 128 + wave * 32 + nt * 16 + ln] = l;
        float rl = 1.0f / l;
        float rlr[4];
        #pragma unroll
        for (int r = 0; r < 4; r++) rlr[r] = __shfl(rl, quad * 4 + r, 64);
        for (int dt = 0; dt < 4; dt++)
            for (int r = 0; r < 4; r++) {
                int q = wave * 32 + nt * 16 + quad * 4 + r;
                Cw[q * 64 + dt * 16 + ln] = (_Float16)(Oacc[nt][dt][r] * rlr[r]);
            }
    }
}

// ---------------------------------------------------------------------------
// Combine: ctx = w0*C0 + w1*C1, w_ks = l_ks/(l0+l1). Grid 512 tiles.
// ---------------------------------------------------------------------------
__global__ __launch_bounds__(256) void combine_kernel(
    const _Float16* __restrict__ Cpart, const float* __restrict__ Lpart,
    unsigned short* __restrict__ ctx)
{
    const int t = threadIdx.x;
    const int tile = blockIdx.x;              // (b*8+h)*32+qt
    const int qt = tile & 31, h = (tile >> 5) & 7, b = tile >> 8;
    __shared__ float w0s[128], w1s[128];
    if (t < 128) {
        float l0 = Lpart[(tile * 2 + 0) * 128 + t];
        float l1 = Lpart[(tile * 2 + 1) * 128 + t];
        float inv = 1.0f / (l0 + l1);
        w0s[t] = l0 * inv;
        w1s[t] = l1 * inv;
    }
    __syncthreads();
    const _Float16* C0 = Cpart + (size_t)(tile * 2) * (128 * 64);
    const _Float16* C1 = C0 + 128 * 64;
    for (int i = 0; i < 8; i++) {
        int e = (i * 256 + t) * 4;
        int q = e >> 6, d = e & 63;
        half2v a0 = *(const half2v*)(C0 + e);
        half2v a1 = *(const half2v*)(C0 + e + 2);
        half2v b0 = *(const half2v*)(C1 + e);
        half2v b1 = *(const half2v*)(C1 + e + 2);
        float w0 = w0s[q], w1 = w1s[q];
        float v0 = w0 * (float)a0[0] + w1 * (float)b0[0];
        float v1 = w0 * (float)a0[1] + w1 * (float)b0[1];
        float v2 = w0 * (float)a1[0] + w1 * (float)b1[0];
        float v3 = w0 * (float)a1[1] + w1 * (float)b1[1];
        uint2 o;
        o.x = pack_bf16(v0, v1);
        o.y = pack_bf16(v2, v3);
        *(uint2*)&ctx[((size_t)b * S_LEN + qt * 128 + q) * HTOT + h * HD + d] = o;
    }
}

// ---------------------------------------------------------------------------
// Projection GEMM: out[m][n] = sum_k ctx[m][k] * W[n][k] + bias[n]
// ---------------------------------------------------------------------------
__global__ __launch_bounds__(256) void proj_kernel(
    const unsigned short* __restrict__ A,  // ctx bf16 [8192 x 512]
    const float* __restrict__ W,           // [512 x 512] fp32
    const float* __restrict__ bias,        // [512]
    float* __restrict__ out)               // [8192 x 512] fp32
{
    __shared__ unsigned short Ash[128 * 40];
    __shared__ unsigned short Bsh[128 * 40];
    const int tid = threadIdx.x;
    const int wave = tid >> 6, lane = tid & 63, quad = lane >> 4, ln = lane & 15;
    const int wr = wave >> 1, wc = wave & 1;
    const int mblock = blockIdx.y * 128;
    const int nblock = blockIdx.x * 128;

    floatx4 acc[4][4];
    for (int i = 0; i < 4; i++)
        for (int j = 0; j < 4; j++) acc[i][j] = (floatx4){0.f, 0.f, 0.f, 0.f};

    for (int kt = 0; kt < 512 / 32; ++kt) {
        const int k0 = kt * 32;
        __syncthreads();
        for (int i = 0; i < 2; i++) {
            int idx = tid + i * 256;
            int r = idx >> 2, c8 = idx & 3;
            short8 v = *(const short8*)&A[(size_t)(mblock + r) * 512 + k0 + c8 * 8];
            *(short8*)&Ash[r * 40 + c8 * 8] = v;
        }
        for (int i = 0; i < 4; i++) {
            int idx = tid + i * 256;
            int r = idx >> 3, c4 = idx & 7;
            float4 v = *(const float4*)&W[(size_t)(nblock + r) * 512 + k0 + c4 * 4];
            uint2 o;
            o.x = pack_bf16(v.x, v.y);
            o.y = pack_bf16(v.z, v.w);
            *(uint2*)&Bsh[r * 40 + c4 * 4] = o;
        }
        __syncthreads();
        short8 af[4], bf[4];
        for (int i = 0; i < 4; i++)
            af[i] = *(const short8*)&Ash[(wr * 64 + i * 16 + ln) * 40 + quad * 8];
        for (int j = 0; j < 4; j++)
            bf[j] = *(const short8*)&Bsh[(wc * 64 + j * 16 + ln) * 40 + quad * 8];
        for (int i = 0; i < 4; i++)
            for (int j = 0; j < 4; j++)
                acc[i][j] = __builtin_amdgcn_mfma_f32_16x16x32_bf16(af[i], bf[j], acc[i][j], 0, 0, 0);
    }

    for (int i = 0; i < 4; i++) {
        int row = mblock + wr * 64 + i * 16 + quad * 4;
        for (int j = 0; j < 4; j++) {
            int col = nblock + wc * 64 + j * 16 + ln;
            float bv = bias[col];
            for (int r = 0; r < 4; r++)
                out[(size_t)(row + r) * 512 + col] = acc[i][j][r] + bv;
        }
    }
}

extern "C" void kernel_launch(void* const* d_in, const int* in_sizes, int n_in,
                              void* d_out, int out_size, void* d_ws, size_t ws_size,
                              hipStream_t stream) {
    const float* Q    = (const float*)d_in[0];
    const float* K    = (const float*)d_in[1];
    const float* V    = (const float*)d_in[2];
    const float* sig  = (const float*)d_in[3];
    const float* lam  = (const float*)d_in[4];
    const float* W    = (const float*)d_in[5];
    const float* bias = (const float*)d_in[6];

    unsigned short* ctx = (unsigned short*)d_ws;                        // 8 MB
    unsigned short* K16 = (unsigned short*)((char*)d_ws + (8u << 20));  // 8 MB
    unsigned short* Vt  = (unsigned short*)((char*)d_ws + (16u << 20)); // 8 MB
    float* Lpart        = (float*)((char*)d_ws + (24u << 20));          // 512 KB
    _Float16* Cpart     = (_Float16*)d_out;   // 16 MB scratch, overwritten by proj
    float* out = (float*)d_out;

    prep_kernel<<<dim3(3072), dim3(256), 0, stream>>>(K, K16, V, Vt);
    attn_kernel<<<dim3(1024), dim3(256), 0, stream>>>(Q, K16, Vt, sig, lam, Cpart, Lpart);
    combine_kernel<<<dim3(512), dim3(256), 0, stream>>>(Cpart, Lpart, ctx);
    proj_kernel<<<dim3(4, 64), dim3(256), 0, stream>>>(ctx, W, bias, out);
}

// Round 5
// 232.804 us; speedup vs baseline: 1.1692x; 1.0633x over previous
//
#include <hip/hip_runtime.h>
#include <hip/hip_bf16.h>

// VolatilityModulatedAttention: B=2, S=4096, H=512, NH=8, HD=64
// Round 4: K/V staging via global_load_lds(16B) DMA into unpadded swizzled
// [64][64] LDS tiles (XOR-swizzle on the fetch side keeps frag reads
// conflict-free); proj 64x128 tiles (512 blocks, 2/CU).

#define S_LEN 4096
#define NHEAD 8
#define HD 64
#define HTOT 512

typedef __attribute__((ext_vector_type(8))) short short8;
typedef __attribute__((ext_vector_type(4))) float floatx4;
typedef __attribute__((ext_vector_type(2))) _Float16 half2v;

#if __has_builtin(__builtin_amdgcn_exp2f)
#define EXP2F(x) __builtin_amdgcn_exp2f(x)
#else
#define EXP2F(x) exp2f(x)
#endif

// pack two fp32 -> two bf16 in one dword (round-half-up)
__device__ __forceinline__ unsigned pack_bf16(float a, float b) {
    unsigned ua = __builtin_bit_cast(unsigned, a) + 0x8000u;
    unsigned ub = __builtin_bit_cast(unsigned, b) + 0x8000u;
    return __builtin_amdgcn_perm(ub, ua, 0x07060302u);
}

__device__ __forceinline__ unsigned short f2bf(float x) {
    unsigned u = __builtin_bit_cast(unsigned, x) + 0x8000u;
    return (unsigned short)(u >> 16);
}

// async 16B global -> LDS (wave-uniform base + lane*16 semantics)
__device__ __forceinline__ void async16(const unsigned short* g, unsigned short* l) {
    __builtin_amdgcn_global_load_lds(
        (const __attribute__((address_space(1))) unsigned int*)g,
        (__attribute__((address_space(3))) unsigned int*)l, 16, 0, 0);
}

// ---------------------------------------------------------------------------
// Fused prepass. Blocks [0,2048): K fp32 -> bf16. Blocks [2048,3072):
// V fp32 [B,S,512] -> bf16 per-head transpose Vt[B*8][64][4096].
// ---------------------------------------------------------------------------
__global__ __launch_bounds__(256) void prep_kernel(
    const float* __restrict__ K, unsigned short* __restrict__ K16,
    const float* __restrict__ V, unsigned short* __restrict__ Vt)
{
    const int tid = threadIdx.x;
    if (blockIdx.x < 2048) {
        size_t i = ((size_t)blockIdx.x * 256 + tid) * 8;
        float4 a = *(const float4*)(K + i);
        float4 b = *(const float4*)(K + i + 4);
        unsigned o[4] = {pack_bf16(a.x, a.y), pack_bf16(a.z, a.w),
                         pack_bf16(b.x, b.y), pack_bf16(b.z, b.w)};
        *(short8*)(K16 + i) = *(short8*)o;
    } else {
        __shared__ unsigned short T[64 * 66];   // [d][s]
        const int blk = blockIdx.x - 2048;
        const int st = blk & 63;
        const int bh = blk >> 6;
        const int b = bh >> 3, h = bh & 7;
        const float* src = V + ((size_t)b * S_LEN + st * 64) * HTOT + h * HD;
        for (int i = 0; i < 4; i++) {
            int idx = tid + i * 256;
            int s = idx >> 4, c4 = idx & 15;
            float4 v = *(const float4*)(src + (size_t)s * HTOT + c4 * 4);
            T[(c4 * 4 + 0) * 66 + s] = f2bf(v.x);
            T[(c4 * 4 + 1) * 66 + s] = f2bf(v.y);
            T[(c4 * 4 + 2) * 66 + s] = f2bf(v.z);
            T[(c4 * 4 + 3) * 66 + s] = f2bf(v.w);
        }
        __syncthreads();
        unsigned short* dst = Vt + ((size_t)bh * 64) * S_LEN + st * 64;
        for (int i = 0; i < 2; i++) {
            int idx = tid + i * 256;
            int d = idx >> 3, c8 = idx & 7;
            uint2 lo = *(const uint2*)&T[d * 66 + c8 * 8];
            uint2 hi = *(const uint2*)&T[d * 66 + c8 * 8 + 4];
            unsigned o[4] = {lo.x, lo.y, hi.x, hi.y};
            *(short8*)(dst + (size_t)d * S_LEN + c8 * 8) = *(short8*)o;
        }
    }
}

// ---------------------------------------------------------------------------
// Flash attention, K-split x2. Grid: 1024 = B(2)*NH(8)*qt(32)*ks(2).
// K/V tiles: unpadded [64][64] bf16, DMA-staged with XOR chunk swizzle:
//   LDS[r][c] holds row r, logical 16B-chunk (c ^ (r&7)).
// ---------------------------------------------------------------------------
__global__ __launch_bounds__(256) void attn_kernel(
    const float* __restrict__ Q, const unsigned short* __restrict__ K16,
    const unsigned short* __restrict__ Vt,
    const float* __restrict__ risk_sigma, const float* __restrict__ risk_lambda,
    _Float16* __restrict__ Cpart, float* __restrict__ Lpart)
{
    __shared__ unsigned short QPsh[128 * 72];   // Q tile (stride 72), then per-wave P
    __shared__ unsigned short Ksh[64 * 64];     // [key][d] swizzled
    __shared__ unsigned short Vsh[64 * 64];     // [d][key] swizzled

    const int tid  = threadIdx.x;
    const int wave = tid >> 6;
    const int lane = tid & 63;
    const int quad = lane >> 4;
    const int ln   = lane & 15;
    const int sw   = ln & 7;    // frag-read swizzle key (row&7 == ln&7)

    const int bid = blockIdx.x;                 // = ((b*8+h)*32+qt)*2+ks
    const int ks  = bid & 1;
    const int qt  = (bid >> 1) & 31;
    const int h   = (bid >> 6) & 7;
    const int b   = bid >> 9;
    const int qbase = qt * 128;

    float sig = risk_sigma[b];
    sig = fminf(fmaxf(sig, 0.001f), 0.2f);
    const float sn   = (sig - 0.001f) * (1.0f / 0.199f);
    const float coef = risk_lambda[0] * 0.1f * sn;
    const float nc2 = -coef * (1.0f / 4096.0f) * (1.0f / 4096.0f) * 1.4426950408889634f;
    const float qscale = 0.125f * 1.4426950408889634f;  // 1/8 / ln2

    const float* Qb = Q + (size_t)b * S_LEN * HTOT + (size_t)h * HD;
    const unsigned short* Kb = K16 + (size_t)b * S_LEN * HTOT + (size_t)h * HD;
    const unsigned short* Vb = Vt + ((size_t)(b * 8 + h) * 64) * S_LEN;

    // ---- stage Q tile (128 x 64), prescaled fp32 -> bf16 ----
    for (int i = 0; i < 8; i++) {
        int idx = tid + i * 256;
        int r = idx >> 4, c4 = idx & 15;
        float4 v = *(const float4*)(Qb + (size_t)(qbase + r) * HTOT + c4 * 4);
        uint2 o;
        o.x = pack_bf16(v.x * qscale, v.y * qscale);
        o.y = pack_bf16(v.z * qscale, v.w * qscale);
        *(uint2*)&QPsh[r * 72 + c4 * 4] = o;
    }
    __syncthreads();

    short8 qf[2][2];
    for (int nt = 0; nt < 2; nt++) {
        qf[nt][0] = *(const short8*)&QPsh[(wave * 32 + nt * 16 + ln) * 72 + quad * 8];
        qf[nt][1] = *(const short8*)&QPsh[(wave * 32 + nt * 16 + ln) * 72 + 32 + quad * 8];
    }
    unsigned short* Pw = &QPsh[wave * 32 * 72];   // wave-private P [32 q][72]

    floatx4 Oacc[2][4];
    for (int nt = 0; nt < 2; nt++)
        for (int dt = 0; dt < 4; dt++) Oacc[nt][dt] = (floatx4){0.f, 0.f, 0.f, 0.f};
    float lp[2] = {0.f, 0.f};

    const int qa = qbase + wave * 32;

    // DMA staging lane geometry (constant across tiles)
    const int rl  = lane >> 3;                  // row-in-slice 0..7
    const int c8g = ((lane & 7) ^ rl) << 3;     // swizzled global chunk (shorts)

    for (int kt = ks * 32; kt < ks * 32 + 32; ++kt) {
        const int kbase = kt * 64;
        __syncthreads();   // prev tile's frag reads done
        {
            const unsigned short* gk = Kb + (size_t)(kbase + wave * 8 + rl) * HTOT + c8g;
            const unsigned short* gv = Vb + (size_t)(wave * 8 + rl) * S_LEN + kbase + c8g;
            async16(gk,              &Ksh[wave * 512 + lane * 8]);
            async16(gk + 32 * HTOT,  &Ksh[(wave + 4) * 512 + lane * 8]);
            async16(gv,              &Vsh[wave * 512 + lane * 8]);
            async16(gv + 32 * S_LEN, &Vsh[(wave + 4) * 512 + lane * 8]);
        }
        __syncthreads();   // drains vmcnt -> tiles visible

        // ---- S^T = K * Q^T, softmax, packed b64 P write ----
        const float dq = (float)(qa + ln - kbase);
        for (int jt = 0; jt < 4; jt++) {
            const int krow = (jt * 16 + ln) * 64;
            short8 ak0 = *(const short8*)&Ksh[krow + ((quad ^ sw) << 3)];
            short8 ak1 = *(const short8*)&Ksh[krow + (((quad + 4) ^ sw) << 3)];
            #pragma unroll
            for (int nt = 0; nt < 2; nt++) {
                floatx4 s = (floatx4){0.f, 0.f, 0.f, 0.f};
                s = __builtin_amdgcn_mfma_f32_16x16x32_bf16(ak0, qf[nt][0], s, 0, 0, 0);
                s = __builtin_amdgcn_mfma_f32_16x16x32_bf16(ak1, qf[nt][1], s, 0, 0, 0);
                float d = dq + (float)(nt * 16 - jt * 16 - quad * 4);
                float p[4];
                #pragma unroll
                for (int r = 0; r < 4; r++) {
                    float arg = __builtin_fmaf(nc2, d * d, s[r]);
                    p[r] = EXP2F(arg);
                    lp[nt] += p[r];
                    d -= 1.0f;
                }
                uint2 o;
                o.x = pack_bf16(p[0], p[1]);
                o.y = pack_bf16(p[2], p[3]);
                *(uint2*)&Pw[(nt * 16 + ln) * 72 + jt * 16 + quad * 4] = o;
            }
        }
        asm volatile("s_waitcnt lgkmcnt(0)" ::: "memory");
        __builtin_amdgcn_wave_barrier();

        // ---- PV (V-frags reused across subtiles) ----
        short8 pf[2][2];
        for (int nt = 0; nt < 2; nt++) {
            pf[nt][0] = *(const short8*)&Pw[(nt * 16 + ln) * 72 + quad * 8];
            pf[nt][1] = *(const short8*)&Pw[(nt * 16 + ln) * 72 + 32 + quad * 8];
        }
        for (int dt = 0; dt < 4; dt++) {
            const int vrow = (dt * 16 + ln) * 64;
            short8 bv0 = *(const short8*)&Vsh[vrow + ((quad ^ sw) << 3)];
            short8 bv1 = *(const short8*)&Vsh[vrow + (((quad + 4) ^ sw) << 3)];
            #pragma unroll
            for (int nt = 0; nt < 2; nt++) {
                Oacc[nt][dt] = __builtin_amdgcn_mfma_f32_16x16x32_bf16(pf[nt][0], bv0, Oacc[nt][dt], 0, 0, 0);
                Oacc[nt][dt] = __builtin_amdgcn_mfma_f32_16x16x32_bf16(pf[nt][1], bv1, Oacc[nt][dt], 0, 0, 0);
            }
        }
    }

    // ---- epilogue: per-half l, normalized fp16 partial ctx ----
    _Float16* Cw = Cpart + (size_t)bid * (128 * 64);
    for (int nt = 0; nt < 2; nt++) {
        float l = lp[nt];
        l += __shfl_xor(l, 16, 64);
        l += __shfl_xor(l, 32, 64);
        if (quad == 0)
            Lpart[bid * 128 + wave * 32 + nt * 16 + ln] = l;
        float rl4 = 1.0f / l;
        float rlr[4];
        #pragma unroll
        for (int r = 0; r < 4; r++) rlr[r] = __shfl(rl4, quad * 4 + r, 64);
        for (int dt = 0; dt < 4; dt++)
            for (int r = 0; r < 4; r++) {
                int q = wave * 32 + nt * 16 + quad * 4 + r;
                Cw[q * 64 + dt * 16 + ln] = (_Float16)(Oacc[nt][dt][r] * rlr[r]);
            }
    }
}

// ---------------------------------------------------------------------------
// Combine: ctx = w0*C0 + w1*C1, w_ks = l_ks/(l0+l1). Grid 512 tiles.
// ---------------------------------------------------------------------------
__global__ __launch_bounds__(256) void combine_kernel(
    const _Float16* __restrict__ Cpart, const float* __restrict__ Lpart,
    unsigned short* __restrict__ ctx)
{
    const int t = threadIdx.x;
    const int tile = blockIdx.x;              // (b*8+h)*32+qt
    const int qt = tile & 31, h = (tile >> 5) & 7, b = tile >> 8;
    __shared__ float w0s[128], w1s[128];
    if (t < 128) {
        float l0 = Lpart[(tile * 2 + 0) * 128 + t];
        float l1 = Lpart[(tile * 2 + 1) * 128 + t];
        float inv = 1.0f / (l0 + l1);
        w0s[t] = l0 * inv;
        w1s[t] = l1 * inv;
    }
    __syncthreads();
    const _Float16* C0 = Cpart + (size_t)(tile * 2) * (128 * 64);
    const _Float16* C1 = C0 + 128 * 64;
    for (int i = 0; i < 8; i++) {
        int e = (i * 256 + t) * 4;
        int q = e >> 6, d = e & 63;
        half2v a0 = *(const half2v*)(C0 + e);
        half2v a1 = *(const half2v*)(C0 + e + 2);
        half2v b0 = *(const half2v*)(C1 + e);
        half2v b1 = *(const half2v*)(C1 + e + 2);
        float w0 = w0s[q], w1 = w1s[q];
        float v0 = w0 * (float)a0[0] + w1 * (float)b0[0];
        float v1 = w0 * (float)a0[1] + w1 * (float)b0[1];
        float v2 = w0 * (float)a1[0] + w1 * (float)b1[0];
        float v3 = w0 * (float)a1[1] + w1 * (float)b1[1];
        uint2 o;
        o.x = pack_bf16(v0, v1);
        o.y = pack_bf16(v2, v3);
        *(uint2*)&ctx[((size_t)b * S_LEN + qt * 128 + q) * HTOT + h * HD + d] = o;
    }
}

// ---------------------------------------------------------------------------
// Projection GEMM: out[m][n] = sum_k ctx[m][k] * W[n][k] + bias[n]
// 64x128 tiles, grid (4,128) = 512 blocks (2/CU). 4 waves = 2x2 of 32x64.
// ---------------------------------------------------------------------------
__global__ __launch_bounds__(256) void proj_kernel(
    const unsigned short* __restrict__ A,  // ctx bf16 [8192 x 512]
    const float* __restrict__ W,           // [512 x 512] fp32
    const float* __restrict__ bias,        // [512]
    float* __restrict__ out)               // [8192 x 512] fp32
{
    __shared__ unsigned short Ash[64 * 40];
    __shared__ unsigned short Bsh[128 * 40];
    const int tid = threadIdx.x;
    const int wave = tid >> 6, lane = tid & 63, quad = lane >> 4, ln = lane & 15;
    const int wr = wave >> 1, wc = wave & 1;
    const int m0 = blockIdx.y * 64;
    const int nblock = blockIdx.x * 128;

    floatx4 acc[2][4];
    for (int i = 0; i < 2; i++)
        for (int j = 0; j < 4; j++) acc[i][j] = (floatx4){0.f, 0.f, 0.f, 0.f};

    for (int kt = 0; kt < 512 / 32; ++kt) {
        const int k0 = kt * 32;
        __syncthreads();
        {   // A tile: 64 rows x 32 k, one b128 per thread
            int r = tid >> 2, c8 = tid & 3;
            short8 v = *(const short8*)&A[(size_t)(m0 + r) * 512 + k0 + c8 * 8];
            *(short8*)&Ash[r * 40 + c8 * 8] = v;
        }
        for (int i = 0; i < 4; i++) {   // W tile: 128 rows x 32 k, fp32->bf16
            int idx = tid + i * 256;
            int r = idx >> 3, c4 = idx & 7;
            float4 v = *(const float4*)&W[(size_t)(nblock + r) * 512 + k0 + c4 * 4];
            uint2 o;
            o.x = pack_bf16(v.x, v.y);
            o.y = pack_bf16(v.z, v.w);
            *(uint2*)&Bsh[r * 40 + c4 * 4] = o;
        }
        __syncthreads();
        short8 af[2], bf[4];
        for (int i = 0; i < 2; i++)
            af[i] = *(const short8*)&Ash[(wr * 32 + i * 16 + ln) * 40 + quad * 8];
        for (int j = 0; j < 4; j++)
            bf[j] = *(const short8*)&Bsh[(wc * 64 + j * 16 + ln) * 40 + quad * 8];
        for (int i = 0; i < 2; i++)
            for (int j = 0; j < 4; j++)
                acc[i][j] = __builtin_amdgcn_mfma_f32_16x16x32_bf16(af[i], bf[j], acc[i][j], 0, 0, 0);
    }

    for (int i = 0; i < 2; i++) {
        int row = m0 + wr * 32 + i * 16 + quad * 4;
        for (int j = 0; j < 4; j++) {
            int col = nblock + wc * 64 + j * 16 + ln;
            float bv = bias[col];
            for (int r = 0; r < 4; r++)
                out[(size_t)(row + r) * 512 + col] = acc[i][j][r] + bv;
        }
    }
}

extern "C" void kernel_launch(void* const* d_in, const int* in_sizes, int n_in,
                              void* d_out, int out_size, void* d_ws, size_t ws_size,
                              hipStream_t stream) {
    const float* Q    = (const float*)d_in[0];
    const float* K    = (const float*)d_in[1];
    const float* V    = (const float*)d_in[2];
    const float* sig  = (const float*)d_in[3];
    const float* lam  = (const float*)d_in[4];
    const float* W    = (const float*)d_in[5];
    const float* bias = (const float*)d_in[6];

    unsigned short* ctx = (unsigned short*)d_ws;                        // 8 MB
    unsigned short* K16 = (unsigned short*)((char*)d_ws + (8u << 20));  // 8 MB
    unsigned short* Vt  = (unsigned short*)((char*)d_ws + (16u << 20)); // 8 MB
    float* Lpart        = (float*)((char*)d_ws + (24u << 20));          // 512 KB
    _Float16* Cpart     = (_Float16*)d_out;   // 16 MB scratch, overwritten by proj
    float* out = (float*)d_out;

    prep_kernel<<<dim3(3072), dim3(256), 0, stream>>>(K, K16, V, Vt);
    attn_kernel<<<dim3(1024), dim3(256), 0, stream>>>(Q, K16, Vt, sig, lam, Cpart, Lpart);
    combine_kernel<<<dim3(512), dim3(256), 0, stream>>>(Cpart, Lpart, ctx);
    proj_kernel<<<dim3(4, 128), dim3(256), 0, stream>>>(ctx, W, bias, out);
}